// Round 1
// baseline (4679.842 us; speedup 1.0000x reference)
//
#include <hip/hip_runtime.h>
#include <hip/hip_bf16.h>

// Problem constants
#define T_STEPS 64
#define BATCH   1024
#define HID     512
#define GATES   2048          // 4*H
#define KDIM    1024          // IN + H
#define BH      (BATCH*HID)   // 524288
#define THB     (T_STEPS*BATCH*HID)

typedef __attribute__((ext_vector_type(4))) float f32x4;
typedef __attribute__((ext_vector_type(8))) short short8;

__device__ __forceinline__ float sigmoidf_(float x) { return 1.f / (1.f + __expf(-x)); }

// ---------------- weight packing: [w_ih | w_hh] -> bf16 [2048][1024], bias sum ----------------
__global__ void pack_weights(const float* __restrict__ wih0, const float* __restrict__ whh0,
                             const float* __restrict__ wih1, const float* __restrict__ whh1,
                             const float* __restrict__ bih0, const float* __restrict__ bhh0,
                             const float* __restrict__ bih1, const float* __restrict__ bhh1,
                             __hip_bfloat16* __restrict__ w0p, __hip_bfloat16* __restrict__ w1p,
                             float* __restrict__ b0, float* __restrict__ b1)
{
    int idx = blockIdx.x * 256 + threadIdx.x;   // over 2048*1024
    int n = idx >> 10, k = idx & 1023;
    float v0 = (k < 512) ? wih0[n * 512 + k] : whh0[n * 512 + (k - 512)];
    float v1 = (k < 512) ? wih1[n * 512 + k] : whh1[n * 512 + (k - 512)];
    w0p[idx] = __float2bfloat16(v0);
    w1p[idx] = __float2bfloat16(v1);
    if (idx < GATES) {
        b0[idx] = bih0[idx] + bhh0[idx];
        b1[idx] = bih1[idx] + bhh1[idx];
    }
}

// ---------------- t=0 prep for layer 0: reset+noise, build xh0 = [bf16(x0) | bf16(h0)] ----------------
__global__ void init_prep(const float* __restrict__ latent, const float* __restrict__ h_t,
                          const float* __restrict__ c_t,
                          const int* __restrict__ reset_mask, const int* __restrict__ clear_mask,
                          const float* __restrict__ noise_std, const float* __restrict__ noise,
                          float* __restrict__ c0c, __hip_bfloat16* __restrict__ xh0)
{
    int idx = blockIdx.x * 256 + threadIdx.x;   // over BH
    int m = idx >> 9, j = idx & 511;
    bool msk = (reset_mask[m * T_STEPS] | clear_mask[m * T_STEPS]) != 0;
    float nv = noise[idx] * noise_std[m * T_STEPS];          // noise[0,0,m,j]
    float h0v = (msk ? 0.f : h_t[idx]) + nv;
    float c0v = (msk ? 0.f : c_t[idx]) + nv;
    c0c[idx] = c0v;
    xh0[m * KDIM + j]       = __float2bfloat16(latent[idx]); // latent[0,m,j]
    xh0[m * KDIM + 512 + j] = __float2bfloat16(h0v);
}

// ---------------- bf16 MFMA GEMM: C[m][n] = sum_k A[m][k]*W[n][k] + bias[n] ----------------
// M=1024, N=2048, K=1024. Block tile 64x64, BK=64, 4 waves each doing one 16-row strip x 4 col tiles.
__global__ __launch_bounds__(256) void gemm_gates(
    const __hip_bfloat16* __restrict__ A,   // [1024][1024] bf16 row-major
    const __hip_bfloat16* __restrict__ W,   // [2048][1024] bf16 row-major
    const float* __restrict__ bias,         // [2048]
    float* __restrict__ C)                  // [1024][2048] fp32
{
    __shared__ __align__(16) short As[64 * 72];
    __shared__ __align__(16) short Bs[64 * 72];
    const int tid  = threadIdx.x;
    const int m0   = blockIdx.y * 64;
    const int n0   = blockIdx.x * 64;
    const int lane = tid & 63;
    const int wave = tid >> 6;
    const int lr   = lane & 15;   // A row / B row (=col of C)
    const int lq   = lane >> 4;   // k-quad

    f32x4 acc[4];
#pragma unroll
    for (int i = 0; i < 4; ++i) acc[i] = (f32x4){0.f, 0.f, 0.f, 0.f};

    const short* Ag = (const short*)A;
    const short* Wg = (const short*)W;

    for (int k0 = 0; k0 < KDIM; k0 += 64) {
#pragma unroll
        for (int i = 0; i < 2; ++i) {
            int c  = tid + i * 256;          // 512 chunks of 8 bf16
            int r  = c >> 3;
            int kk = (c & 7) * 8;
            *(short8*)&As[r * 72 + kk] = *(const short8*)&Ag[(size_t)(m0 + r) * KDIM + k0 + kk];
            *(short8*)&Bs[r * 72 + kk] = *(const short8*)&Wg[(size_t)(n0 + r) * KDIM + k0 + kk];
        }
        __syncthreads();
#pragma unroll
        for (int kk = 0; kk < 64; kk += 32) {
            short8 a = *(const short8*)&As[(wave * 16 + lr) * 72 + kk + lq * 8];
#pragma unroll
            for (int nt = 0; nt < 4; ++nt) {
                short8 b = *(const short8*)&Bs[(nt * 16 + lr) * 72 + kk + lq * 8];
                acc[nt] = __builtin_amdgcn_mfma_f32_16x16x32_bf16(a, b, acc[nt], 0, 0, 0);
            }
        }
        __syncthreads();
    }
#pragma unroll
    for (int nt = 0; nt < 4; ++nt) {
        int n = n0 + nt * 16 + lr;
        float bv = bias[n];
#pragma unroll
        for (int r = 0; r < 4; ++r) {
            int m = m0 + wave * 16 + lq * 4 + r;
            C[(size_t)m * GATES + n] = acc[nt][r] + bv;
        }
    }
}

// ---------------- layer-0 cell + layer-1 prep (same timestep t) ----------------
__global__ void cell0_prep1(const float* __restrict__ gates,
                            float* __restrict__ h0c, float* __restrict__ c0c,
                            const float* __restrict__ h1src, const float* __restrict__ c1src,
                            float* __restrict__ c1c,
                            __hip_bfloat16* __restrict__ xh1,
                            const int* __restrict__ reset_mask, const int* __restrict__ clear_mask,
                            const float* __restrict__ noise_std, const float* __restrict__ noise,
                            int t)
{
    int idx = blockIdx.x * 256 + threadIdx.x;
    int m = idx >> 9, j = idx & 511;
    const float* gr = gates + (size_t)m * GATES + j;
    float gi = gr[0], gf = gr[512], gg = gr[1024], go = gr[1536];
    float c  = c0c[idx];
    float cn = sigmoidf_(gf) * c + sigmoidf_(gi) * tanhf(gg);
    float hn = sigmoidf_(go) * tanhf(cn);
    h0c[idx] = hn;
    c0c[idx] = cn;
    xh1[m * KDIM + j] = __float2bfloat16(hn);
    // layer-1 reset/noise at step t
    bool msk = (reset_mask[m * T_STEPS + t] | clear_mask[m * T_STEPS + t]) != 0;
    float nv = noise[((size_t)(t * 2 + 1) * BATCH + m) * HID + j] * noise_std[m * T_STEPS + t];
    float h1v = (msk ? 0.f : h1src[idx]) + nv;
    float c1v = (msk ? 0.f : c1src[idx]) + nv;
    c1c[idx] = c1v;
    xh1[m * KDIM + 512 + j] = __float2bfloat16(h1v);
}

// ---------------- layer-1 cell + layer-0 prep (timestep t+1); writes hidden[t] ----------------
__global__ void cell1_prep0(const float* __restrict__ gates,
                            float* __restrict__ h1c, float* __restrict__ c1c,
                            float* __restrict__ hidden,
                            const float* __restrict__ latent,
                            float* __restrict__ h0c, float* __restrict__ c0c,
                            __hip_bfloat16* __restrict__ xh0,
                            const int* __restrict__ reset_mask, const int* __restrict__ clear_mask,
                            const float* __restrict__ noise_std, const float* __restrict__ noise,
                            int t, int do_prep)
{
    int idx = blockIdx.x * 256 + threadIdx.x;
    int m = idx >> 9, j = idx & 511;
    const float* gr = gates + (size_t)m * GATES + j;
    float gi = gr[0], gf = gr[512], gg = gr[1024], go = gr[1536];
    float c  = c1c[idx];
    float cn = sigmoidf_(gf) * c + sigmoidf_(gi) * tanhf(gg);
    float hn = sigmoidf_(go) * tanhf(cn);
    hidden[(size_t)t * BH + idx] = hn;
    h1c[idx] = hn;
    c1c[idx] = cn;
    if (do_prep) {
        int tn = t + 1;
        bool msk = (reset_mask[m * T_STEPS + tn] | clear_mask[m * T_STEPS + tn]) != 0;
        float nv = noise[((size_t)(tn * 2) * BATCH + m) * HID + j] * noise_std[m * T_STEPS + tn];
        float h0v = (msk ? 0.f : h0c[idx]) + nv;
        float c0v = (msk ? 0.f : c0c[idx]) + nv;
        c0c[idx] = c0v;
        xh0[m * KDIM + j]       = __float2bfloat16(latent[(size_t)tn * BH + idx]);
        xh0[m * KDIM + 512 + j] = __float2bfloat16(h0v);
    }
}

// ---------------- final h/c -> d_out ----------------
__global__ void write_finals(const float* __restrict__ h0c, const float* __restrict__ h1c,
                             const float* __restrict__ c0c, const float* __restrict__ c1c,
                             float* __restrict__ out)
{
    int idx = blockIdx.x * 256 + threadIdx.x;
    out[THB + idx]          = h0c[idx];
    out[THB + BH + idx]     = h1c[idx];
    out[THB + 2 * BH + idx] = c0c[idx];
    out[THB + 3 * BH + idx] = c1c[idx];
}

extern "C" void kernel_launch(void* const* d_in, const int* in_sizes, int n_in,
                              void* d_out, int out_size, void* d_ws, size_t ws_size,
                              hipStream_t stream)
{
    const float* latent     = (const float*)d_in[0];
    const float* h_t        = (const float*)d_in[1];
    const float* c_t        = (const float*)d_in[2];
    const int*   reset_mask = (const int*)d_in[3];   // (1,B,T,1) flat b*T+t
    const int*   clear_mask = (const int*)d_in[4];   // (B,T)     flat b*T+t
    const float* noise_std  = (const float*)d_in[5]; // (B,T)     flat b*T+t
    const float* noise      = (const float*)d_in[6]; // (T,L,B,H)
    const float* wih0 = (const float*)d_in[7];
    const float* whh0 = (const float*)d_in[8];
    const float* bih0 = (const float*)d_in[9];
    const float* bhh0 = (const float*)d_in[10];
    const float* wih1 = (const float*)d_in[11];
    const float* whh1 = (const float*)d_in[12];
    const float* bih1 = (const float*)d_in[13];
    const float* bhh1 = (const float*)d_in[14];
    float* out = (float*)d_out;

    char* ws = (char*)d_ws;
    size_t off = 0;
    auto alloc = [&](size_t bytes) -> void* {
        void* p = ws + off;
        off += (bytes + 255) & ~(size_t)255;
        return p;
    };
    __hip_bfloat16* w0p = (__hip_bfloat16*)alloc((size_t)GATES * KDIM * 2);
    __hip_bfloat16* w1p = (__hip_bfloat16*)alloc((size_t)GATES * KDIM * 2);
    float* b0 = (float*)alloc(GATES * 4);
    float* b1 = (float*)alloc(GATES * 4);
    __hip_bfloat16* xh0 = (__hip_bfloat16*)alloc((size_t)BATCH * KDIM * 2);
    __hip_bfloat16* xh1 = (__hip_bfloat16*)alloc((size_t)BATCH * KDIM * 2);
    float* gates0 = (float*)alloc((size_t)BATCH * GATES * 4);
    float* gates1 = (float*)alloc((size_t)BATCH * GATES * 4);
    float* h0c = (float*)alloc((size_t)BH * 4);
    float* c0c = (float*)alloc((size_t)BH * 4);
    float* h1c = (float*)alloc((size_t)BH * 4);
    float* c1c = (float*)alloc((size_t)BH * 4);

    pack_weights<<<(GATES * KDIM) / 256, 256, 0, stream>>>(
        wih0, whh0, wih1, whh1, bih0, bhh0, bih1, bhh1, w0p, w1p, b0, b1);
    init_prep<<<BH / 256, 256, 0, stream>>>(
        latent, h_t, c_t, reset_mask, clear_mask, noise_std, noise, c0c, xh0);

    dim3 ggrid(GATES / 64, BATCH / 64);   // (32,16) = 512 blocks
    for (int t = 0; t < T_STEPS; ++t) {
        gemm_gates<<<ggrid, 256, 0, stream>>>(xh0, w0p, b0, gates0);
        cell0_prep1<<<BH / 256, 256, 0, stream>>>(
            gates0, h0c, c0c,
            (t == 0) ? (h_t + BH) : h1c, (t == 0) ? (c_t + BH) : c1c,
            c1c, xh1, reset_mask, clear_mask, noise_std, noise, t);
        gemm_gates<<<ggrid, 256, 0, stream>>>(xh1, w1p, b1, gates1);
        cell1_prep0<<<BH / 256, 256, 0, stream>>>(
            gates1, h1c, c1c, out, latent, h0c, c0c, xh0,
            reset_mask, clear_mask, noise_std, noise, t, (t + 1 < T_STEPS) ? 1 : 0);
    }
    write_finals<<<BH / 256, 256, 0, stream>>>(h0c, h1c, c0c, c1c, out);
}

// Round 2
// 2968.785 us; speedup vs baseline: 1.5763x; 1.5763x over previous
//
#include <hip/hip_runtime.h>
#include <hip/hip_bf16.h>

// Problem constants
#define T_STEPS 64
#define BATCH   1024
#define HID     512
#define GATES   2048          // 4*H
#define KDIM    1024          // IN + H
#define BH      (BATCH*HID)   // 524288
#define THB     (T_STEPS*BATCH*HID)

typedef __attribute__((ext_vector_type(4))) float f32x4;
typedef __attribute__((ext_vector_type(8))) short short8;

__device__ __forceinline__ float sigmoidf_(float x) { return 1.f / (1.f + __expf(-x)); }

// ---------------- weight packing: [w_ih | w_hh] -> bf16 [2048][1024], bias sum ----------------
__global__ void pack_weights(const float* __restrict__ wih0, const float* __restrict__ whh0,
                             const float* __restrict__ wih1, const float* __restrict__ whh1,
                             const float* __restrict__ bih0, const float* __restrict__ bhh0,
                             const float* __restrict__ bih1, const float* __restrict__ bhh1,
                             __hip_bfloat16* __restrict__ w0p, __hip_bfloat16* __restrict__ w1p,
                             float* __restrict__ b0, float* __restrict__ b1)
{
    int idx = blockIdx.x * 256 + threadIdx.x;   // over 2048*1024
    int n = idx >> 10, k = idx & 1023;
    float v0 = (k < 512) ? wih0[n * 512 + k] : whh0[n * 512 + (k - 512)];
    float v1 = (k < 512) ? wih1[n * 512 + k] : whh1[n * 512 + (k - 512)];
    w0p[idx] = __float2bfloat16(v0);
    w1p[idx] = __float2bfloat16(v1);
    if (idx < GATES) {
        b0[idx] = bih0[idx] + bhh0[idx];
        b1[idx] = bih1[idx] + bhh1[idx];
    }
}

// ---------------- t=0 prep for layer 0: reset+noise, build xh0 = [bf16(x0) | bf16(h0)] ----------------
__global__ void init_prep(const float* __restrict__ latent, const float* __restrict__ h_t,
                          const float* __restrict__ c_t,
                          const int* __restrict__ reset_mask, const int* __restrict__ clear_mask,
                          const float* __restrict__ noise_std, const float* __restrict__ noise,
                          float* __restrict__ c0s, __hip_bfloat16* __restrict__ xh0)
{
    int idx = blockIdx.x * 256 + threadIdx.x;   // over BH
    int m = idx >> 9, j = idx & 511;
    bool msk = (reset_mask[m * T_STEPS] | clear_mask[m * T_STEPS]) != 0;
    float nv = noise[idx] * noise_std[m * T_STEPS];          // noise[0,0,m,j]
    float h0v = (msk ? 0.f : h_t[idx]) + nv;
    float c0v = (msk ? 0.f : c_t[idx]) + nv;
    c0s[idx] = c0v;
    xh0[m * KDIM + j]       = __float2bfloat16(latent[idx]); // latent[0,m,j]
    xh0[m * KDIM + 512 + j] = __float2bfloat16(h0v);
}

// =====================================================================================
// Fused step kernels. GEMM tile: 64 m-rows x (4 gates x 16 j-cols). Grid = 512 blocks
// (16 m-blocks x 32 j-blocks), XCD-swizzled so each XCD's 64 blocks share 4 j-blocks
// (per-XCD W working set ~512 KB -> stays L2-resident across all 64 steps).
// Wave w owns m-tile w (16 rows) x all 4 gate n-tiles -> cell math is lane-local.
// =====================================================================================
#define GEMM_PROLOGUE(APTR, WPTR)                                                        \
    __shared__ short As[64 * 72];                                                        \
    __shared__ short Ws[64 * 72];                                                        \
    const int tid  = threadIdx.x;                                                        \
    const int lane = tid & 63;                                                           \
    const int wave = tid >> 6;                                                           \
    const int lr   = lane & 15;                                                          \
    const int lq   = lane >> 4;                                                          \
    const int b    = blockIdx.x;                                                         \
    const int xcd  = b & 7;                                                              \
    const int seq  = b >> 3;                                                             \
    const int jb   = xcd * 4 + (seq >> 4);   /* 0..31 */                                 \
    const int mb   = seq & 15;               /* 0..15 */                                 \
    const int m0   = mb * 64;                                                            \
    const int j0   = jb * 16;                                                            \
    f32x4 acc[4];                                                                        \
    _Pragma("unroll") for (int g = 0; g < 4; ++g) acc[g] = (f32x4){0.f, 0.f, 0.f, 0.f}; \
    const short* Ag = (const short*)(APTR);                                              \
    const short* Wg = (const short*)(WPTR);                                              \
    for (int k0 = 0; k0 < KDIM; k0 += 64) {                                              \
        _Pragma("unroll") for (int i = 0; i < 2; ++i) {                                  \
            int c  = tid + i * 256;                                                      \
            int r  = c >> 3;                                                             \
            int kk = (c & 7) * 8;                                                        \
            *(short8*)&As[r * 72 + kk] = *(const short8*)&Ag[(size_t)(m0 + r) * KDIM + k0 + kk]; \
            int grow = (r >> 4) * 512 + j0 + (r & 15);                                   \
            *(short8*)&Ws[r * 72 + kk] = *(const short8*)&Wg[(size_t)grow * KDIM + k0 + kk]; \
        }                                                                                \
        __syncthreads();                                                                 \
        _Pragma("unroll") for (int kk = 0; kk < 64; kk += 32) {                          \
            short8 a = *(const short8*)&As[(wave * 16 + lr) * 72 + kk + lq * 8];         \
            _Pragma("unroll") for (int g = 0; g < 4; ++g) {                              \
                short8 w = *(const short8*)&Ws[(g * 16 + lr) * 72 + kk + lq * 8];        \
                acc[g] = __builtin_amdgcn_mfma_f32_16x16x32_bf16(a, w, acc[g], 0, 0, 0); \
            }                                                                            \
        }                                                                                \
        __syncthreads();                                                                 \
    }                                                                                    \
    const int j   = j0 + lr;                                                             \
    const float bi = bias[j];                                                            \
    const float bf = bias[512 + j];                                                      \
    const float bg = bias[1024 + j];                                                     \
    const float bo = bias[1536 + j];

// ---- layer-0 step: gates0 GEMM + cell0 + layer-1 input prep (same t) ----
__global__ __launch_bounds__(256) void fused_step0(
    const __hip_bfloat16* __restrict__ A,   // xh0 [1024][1024]
    const __hip_bfloat16* __restrict__ W,   // w0p
    const float* __restrict__ bias,
    float* __restrict__ h0s, float* __restrict__ c0s,
    const float* __restrict__ h1src, const float* __restrict__ c1src,
    float* __restrict__ c1s,
    __hip_bfloat16* __restrict__ xh1,
    const int* __restrict__ reset_mask, const int* __restrict__ clear_mask,
    const float* __restrict__ noise_std, const float* __restrict__ noise,
    int t)
{
    GEMM_PROLOGUE(A, W)
#pragma unroll
    for (int r = 0; r < 4; ++r) {
        int m   = m0 + wave * 16 + lq * 4 + r;
        int idx = m * 512 + j;
        float gi = acc[0][r] + bi, gf = acc[1][r] + bf;
        float gg = acc[2][r] + bg, go = acc[3][r] + bo;
        float c  = c0s[idx];
        float cn = sigmoidf_(gf) * c + sigmoidf_(gi) * tanhf(gg);
        float hn = sigmoidf_(go) * tanhf(cn);
        h0s[idx] = hn;
        c0s[idx] = cn;
        xh1[m * KDIM + j] = __float2bfloat16(hn);
        // layer-1 reset/noise prep for this step
        bool msk = (reset_mask[m * T_STEPS + t] | clear_mask[m * T_STEPS + t]) != 0;
        float nv = noise[((size_t)(t * 2 + 1) * BATCH + m) * HID + j] * noise_std[m * T_STEPS + t];
        float h1v = (msk ? 0.f : h1src[idx]) + nv;
        float c1v = (msk ? 0.f : c1src[idx]) + nv;
        c1s[idx] = c1v;
        xh1[m * KDIM + 512 + j] = __float2bfloat16(h1v);
    }
}

// ---- layer-1 step: gates1 GEMM + cell1 (writes hidden[t]) + layer-0 prep (t+1) ----
__global__ __launch_bounds__(256) void fused_step1(
    const __hip_bfloat16* __restrict__ A,   // xh1 [1024][1024]
    const __hip_bfloat16* __restrict__ W,   // w1p
    const float* __restrict__ bias,
    float* __restrict__ h1s, float* __restrict__ c1s,
    float* __restrict__ hidden,             // d_out
    const float* __restrict__ latent,
    float* __restrict__ h0s, float* __restrict__ c0s,
    __hip_bfloat16* __restrict__ xh0,
    const int* __restrict__ reset_mask, const int* __restrict__ clear_mask,
    const float* __restrict__ noise_std, const float* __restrict__ noise,
    int t, int do_prep)
{
    GEMM_PROLOGUE(A, W)
#pragma unroll
    for (int r = 0; r < 4; ++r) {
        int m   = m0 + wave * 16 + lq * 4 + r;
        int idx = m * 512 + j;
        float gi = acc[0][r] + bi, gf = acc[1][r] + bf;
        float gg = acc[2][r] + bg, go = acc[3][r] + bo;
        float c  = c1s[idx];
        float cn = sigmoidf_(gf) * c + sigmoidf_(gi) * tanhf(gg);
        float hn = sigmoidf_(go) * tanhf(cn);
        hidden[(size_t)t * BH + idx] = hn;
        h1s[idx] = hn;
        c1s[idx] = cn;
        if (do_prep) {
            int tn = t + 1;
            bool msk = (reset_mask[m * T_STEPS + tn] | clear_mask[m * T_STEPS + tn]) != 0;
            float nv = noise[((size_t)(tn * 2) * BATCH + m) * HID + j] * noise_std[m * T_STEPS + tn];
            float h0v = (msk ? 0.f : h0s[idx]) + nv;
            float c0v = (msk ? 0.f : c0s[idx]) + nv;
            c0s[idx] = c0v;
            xh0[m * KDIM + j]       = __float2bfloat16(latent[(size_t)tn * BH + idx]);
            xh0[m * KDIM + 512 + j] = __float2bfloat16(h0v);
        }
    }
}

// ---------------- final h/c -> d_out ----------------
__global__ void write_finals(const float* __restrict__ h0s, const float* __restrict__ h1s,
                             const float* __restrict__ c0s, const float* __restrict__ c1s,
                             float* __restrict__ out)
{
    int idx = blockIdx.x * 256 + threadIdx.x;
    out[THB + idx]          = h0s[idx];
    out[THB + BH + idx]     = h1s[idx];
    out[THB + 2 * BH + idx] = c0s[idx];
    out[THB + 3 * BH + idx] = c1s[idx];
}

extern "C" void kernel_launch(void* const* d_in, const int* in_sizes, int n_in,
                              void* d_out, int out_size, void* d_ws, size_t ws_size,
                              hipStream_t stream)
{
    const float* latent     = (const float*)d_in[0];
    const float* h_t        = (const float*)d_in[1];
    const float* c_t        = (const float*)d_in[2];
    const int*   reset_mask = (const int*)d_in[3];   // (1,B,T,1) flat b*T+t
    const int*   clear_mask = (const int*)d_in[4];   // (B,T)     flat b*T+t
    const float* noise_std  = (const float*)d_in[5]; // (B,T)     flat b*T+t
    const float* noise      = (const float*)d_in[6]; // (T,L,B,H)
    const float* wih0 = (const float*)d_in[7];
    const float* whh0 = (const float*)d_in[8];
    const float* bih0 = (const float*)d_in[9];
    const float* bhh0 = (const float*)d_in[10];
    const float* wih1 = (const float*)d_in[11];
    const float* whh1 = (const float*)d_in[12];
    const float* bih1 = (const float*)d_in[13];
    const float* bhh1 = (const float*)d_in[14];
    float* out = (float*)d_out;

    char* ws = (char*)d_ws;
    size_t off = 0;
    auto alloc = [&](size_t bytes) -> void* {
        void* p = ws + off;
        off += (bytes + 255) & ~(size_t)255;
        return p;
    };
    __hip_bfloat16* w0p = (__hip_bfloat16*)alloc((size_t)GATES * KDIM * 2);
    __hip_bfloat16* w1p = (__hip_bfloat16*)alloc((size_t)GATES * KDIM * 2);
    float* b0 = (float*)alloc(GATES * 4);
    float* b1 = (float*)alloc(GATES * 4);
    __hip_bfloat16* xh0 = (__hip_bfloat16*)alloc((size_t)BATCH * KDIM * 2);
    __hip_bfloat16* xh1 = (__hip_bfloat16*)alloc((size_t)BATCH * KDIM * 2);
    float* h0s = (float*)alloc((size_t)BH * 4);
    float* c0s = (float*)alloc((size_t)BH * 4);
    float* h1s = (float*)alloc((size_t)BH * 4);
    float* c1s = (float*)alloc((size_t)BH * 4);

    pack_weights<<<(GATES * KDIM) / 256, 256, 0, stream>>>(
        wih0, whh0, wih1, whh1, bih0, bhh0, bih1, bhh1, w0p, w1p, b0, b1);
    init_prep<<<BH / 256, 256, 0, stream>>>(
        latent, h_t, c_t, reset_mask, clear_mask, noise_std, noise, c0s, xh0);

    for (int t = 0; t < T_STEPS; ++t) {
        fused_step0<<<512, 256, 0, stream>>>(
            xh0, w0p, b0, h0s, c0s,
            (t == 0) ? (h_t + BH) : h1s, (t == 0) ? (c_t + BH) : c1s,
            c1s, xh1, reset_mask, clear_mask, noise_std, noise, t);
        fused_step1<<<512, 256, 0, stream>>>(
            xh1, w1p, b1, h1s, c1s, out, latent, h0s, c0s, xh0,
            reset_mask, clear_mask, noise_std, noise, t, (t + 1 < T_STEPS) ? 1 : 0);
    }
    write_finals<<<BH / 256, 256, 0, stream>>>(h0s, h1s, c0s, c1s, out);
}